// Round 2
// baseline (29.235 us; speedup 1.0000x reference)
//
#include <hip/hip_runtime.h>

#define ALPHA_C   10.0f
#define INV_BETA  20.0f       // 1/0.05
#define EPS_C     1e-10f
#define FAR_DELTA 1e10f

// One 64-lane wave per ray; lane l handles samples 2l and 2l+1 (d=128).
__global__ __launch_bounds__(256) void volsdf_render_kernel(
    const float* __restrict__ sd,      // [N,128]
    const float* __restrict__ color,   // [N,128,3]
    const float* __restrict__ depth,   // [N,128]
    float* __restrict__ out,           // [N,3]
    int N)
{
    const int wave = (int)((blockIdx.x * blockDim.x + threadIdx.x) >> 6);
    const int lane = (int)(threadIdx.x & 63);
    if (wave >= N) return;

    const size_t base = (size_t)wave * 128 + (size_t)lane * 2;

    // Coalesced vector loads
    const float2 sd2 = *reinterpret_cast<const float2*>(sd + base);
    const float2 dp2 = *reinterpret_cast<const float2*>(depth + base);
    const float* cb  = color + (size_t)wave * 384 + (size_t)lane * 6;
    const float2 c01 = *reinterpret_cast<const float2*>(cb + 0); // r0 g0
    const float2 c23 = *reinterpret_cast<const float2*>(cb + 2); // b0 r1
    const float2 c45 = *reinterpret_cast<const float2*>(cb + 4); // g1 b1

    // deltas: delta_i = depth[i+1] - depth[i]; last sample gets FAR_DELTA
    const float dnext  = __shfl_down(dp2.x, 1, 64);  // depth[2l+2] from lane l+1
    const float delta0 = dp2.y - dp2.x;
    const float delta1 = (lane == 63) ? FAR_DELTA : (dnext - dp2.y);

    // density = ALPHA * LaplaceCDF(-sd): one exp via exp(-|s|/beta)
    const float s0 = -sd2.x, s1 = -sd2.y;
    const float e0 = __expf(-fabsf(s0) * INV_BETA);
    const float e1 = __expf(-fabsf(s1) * INV_BETA);
    const float den0 = ALPHA_C * ((s0 <= 0.0f) ? 0.5f * e0 : 1.0f - 0.5f * e0);
    const float den1 = ALPHA_C * ((s1 <= 0.0f) ? 0.5f * e1 : 1.0f - 0.5f * e1);

    // per-step log transmittance factor
    const float t0 = -den0 * delta0 + EPS_C;
    const float t1 = -den1 * delta1 + EPS_C;

    // Wave-wide inclusive prefix sum of (t0 + t1).
    // NOTE: lane 63's tl is ~-1e11 (FAR_DELTA); its inclusive value is never
    // consumed by any other lane, and we must NOT recover the exclusive sum
    // by subtracting tl (catastrophic cancellation). Use shfl_up(incl, 1).
    const float tl = t0 + t1;
    float incl = tl;
    #pragma unroll
    for (int off = 1; off < 64; off <<= 1) {
        const float up = __shfl_up(incl, off, 64);
        if (lane >= off) incl += up;
    }
    float excl = __shfl_up(incl, 1, 64);   // previous lane's inclusive sum
    if (lane == 0) excl = 0.0f;

    // weights
    const float w0 = __expf(excl)      * (1.0f - __expf(t0));
    const float w1 = __expf(excl + t0) * (1.0f - __expf(t1));

    // weighted color accumulation (layout: r0 g0 b0 r1 g1 b1)
    float accr = w0 * c01.x + w1 * c23.y;
    float accg = w0 * c01.y + w1 * c45.x;
    float accb = w0 * c23.x + w1 * c45.y;

    // wave reduction (64 lanes)
    #pragma unroll
    for (int off = 32; off >= 1; off >>= 1) {
        accr += __shfl_xor(accr, off, 64);
        accg += __shfl_xor(accg, off, 64);
        accb += __shfl_xor(accb, off, 64);
    }

    if (lane == 0) {
        float* o = out + (size_t)wave * 3;
        o[0] = accr;
        o[1] = accg;
        o[2] = accb;
    }
}

extern "C" void kernel_launch(void* const* d_in, const int* in_sizes, int n_in,
                              void* d_out, int out_size, void* d_ws, size_t ws_size,
                              hipStream_t stream) {
    const float* sd    = (const float*)d_in[0];  // signed_distance [N,128]
    const float* color = (const float*)d_in[1];  // color [N,128,3]
    const float* depth = (const float*)d_in[2];  // depth_values [N,128]
    float* out = (float*)d_out;

    const int N = in_sizes[0] / 128;             // 65536
    const int block = 256;                       // 4 waves (rays) per block
    const int grid = (N * 64 + block - 1) / block;
    volsdf_render_kernel<<<grid, block, 0, stream>>>(sd, color, depth, out, N);
}

// Round 3
// 29.107 us; speedup vs baseline: 1.0044x; 1.0044x over previous
//
#include <hip/hip_runtime.h>

#define ALPHA_C   10.0f
#define INV_BETA  20.0f       // 1/0.05
#define EPS_C     1e-10f
#define FAR_DELTA 1e10f

// Half-wave per ray: lanes 0-31 -> ray 2*wave, lanes 32-63 -> ray 2*wave+1.
// Each lane owns 4 consecutive samples -> all loads are 16B dwordx4, and a
// wave's loads for sd/depth/color each cover one contiguous segment
// (2 consecutive rays) -> perfect coalescing at the float4 sweet spot.
__global__ __launch_bounds__(256) void volsdf_render_kernel(
    const float* __restrict__ sd,      // [N,128]
    const float* __restrict__ color,   // [N,128,3]
    const float* __restrict__ depth,   // [N,128]
    float* __restrict__ out,           // [N,3]
    int N)
{
    const int tid  = (int)(blockIdx.x * blockDim.x + threadIdx.x);
    const int wave = tid >> 6;
    const int lane = (int)(threadIdx.x & 63);
    const int half = lane >> 5;        // which ray within the wave
    const int gl   = lane & 31;        // lane within the 32-lane ray group
    const int ray  = wave * 2 + half;
    if (ray >= N) return;

    const size_t rbase = (size_t)ray * 128 + (size_t)gl * 4;
    const float4 sd4 = *reinterpret_cast<const float4*>(sd + rbase);
    const float4 dp4 = *reinterpret_cast<const float4*>(depth + rbase);
    const float* cb  = color + (size_t)ray * 384 + (size_t)gl * 12;
    const float4 f0 = *reinterpret_cast<const float4*>(cb + 0); // r0 g0 b0 r1
    const float4 f1 = *reinterpret_cast<const float4*>(cb + 4); // g1 b1 r2 g2
    const float4 f2 = *reinterpret_cast<const float4*>(cb + 8); // b2 r3 g3 b3

    // deltas: delta_i = depth[i+1]-depth[i]; sample 127 gets FAR_DELTA
    const float dnext  = __shfl_down(dp4.x, 1, 32);  // depth[4gl+4]
    const float delta0 = dp4.y - dp4.x;
    const float delta1 = dp4.z - dp4.y;
    const float delta2 = dp4.w - dp4.z;
    const float delta3 = (gl == 31) ? FAR_DELTA : (dnext - dp4.w);

    // density = ALPHA * LaplaceCDF(-sd): one exp per sample
    const float s0 = -sd4.x, s1 = -sd4.y, s2 = -sd4.z, s3 = -sd4.w;
    const float e0 = __expf(-fabsf(s0) * INV_BETA);
    const float e1 = __expf(-fabsf(s1) * INV_BETA);
    const float e2 = __expf(-fabsf(s2) * INV_BETA);
    const float e3 = __expf(-fabsf(s3) * INV_BETA);
    const float den0 = ALPHA_C * ((s0 <= 0.0f) ? 0.5f * e0 : 1.0f - 0.5f * e0);
    const float den1 = ALPHA_C * ((s1 <= 0.0f) ? 0.5f * e1 : 1.0f - 0.5f * e1);
    const float den2 = ALPHA_C * ((s2 <= 0.0f) ? 0.5f * e2 : 1.0f - 0.5f * e2);
    const float den3 = ALPHA_C * ((s3 <= 0.0f) ? 0.5f * e3 : 1.0f - 0.5f * e3);

    // per-step log transmittance factors
    const float t0 = -den0 * delta0 + EPS_C;
    const float t1 = -den1 * delta1 + EPS_C;
    const float t2 = -den2 * delta2 + EPS_C;
    const float t3 = -den3 * delta3 + EPS_C;

    // in-lane prefix sums; group-wide (width-32) inclusive scan of lane total
    const float p1 = t0;
    const float p2 = t0 + t1;
    const float p3 = p2 + t2;
    const float tl = p3 + t3;          // lane 31's tl ~ -1e11: never consumed
    float incl = tl;
    #pragma unroll
    for (int off = 1; off < 32; off <<= 1) {
        const float up = __shfl_up(incl, off, 32);
        if (gl >= off) incl += up;
    }
    float excl = __shfl_up(incl, 1, 32);   // previous lane's inclusive sum
    if (gl == 0) excl = 0.0f;
    // (do NOT compute excl = incl - tl: catastrophic cancellation at gl==31)

    // weights: T_i = exp(excl + p_i), w_i = T_i * (1 - exp(t_i))
    const float T0  = __expf(excl);
    const float et0 = __expf(t0), et1 = __expf(t1);
    const float et2 = __expf(t2), et3 = __expf(t3);
    const float T1 = T0 * et0;
    const float T2 = T1 * et1;
    const float T3 = T2 * et2;
    const float w0 = T0 * (1.0f - et0);
    const float w1 = T1 * (1.0f - et1);
    const float w2 = T2 * (1.0f - et2);
    const float w3 = T3 * (1.0f - et3);

    // weighted color accumulation
    float accr = w0 * f0.x + w1 * f0.w + w2 * f1.z + w3 * f2.y;
    float accg = w0 * f0.y + w1 * f1.x + w2 * f1.w + w3 * f2.z;
    float accb = w0 * f0.z + w1 * f1.y + w2 * f2.x + w3 * f2.w;

    // reduction within the 32-lane ray group
    #pragma unroll
    for (int off = 16; off >= 1; off >>= 1) {
        accr += __shfl_xor(accr, off, 32);
        accg += __shfl_xor(accg, off, 32);
        accb += __shfl_xor(accb, off, 32);
    }

    if (gl == 0) {
        float* o = out + (size_t)ray * 3;
        o[0] = accr;
        o[1] = accg;
        o[2] = accb;
    }
}

extern "C" void kernel_launch(void* const* d_in, const int* in_sizes, int n_in,
                              void* d_out, int out_size, void* d_ws, size_t ws_size,
                              hipStream_t stream) {
    const float* sd    = (const float*)d_in[0];  // signed_distance [N,128]
    const float* color = (const float*)d_in[1];  // color [N,128,3]
    const float* depth = (const float*)d_in[2];  // depth_values [N,128]
    float* out = (float*)d_out;

    const int N = in_sizes[0] / 128;             // 65536
    const int nWaves = (N + 1) / 2;              // 2 rays per wave
    const int block = 256;
    const int grid = (nWaves * 64 + block - 1) / block;
    volsdf_render_kernel<<<grid, block, 0, stream>>>(sd, color, depth, out, N);
}

// Round 4
// 28.958 us; speedup vs baseline: 1.0096x; 1.0051x over previous
//
#include <hip/hip_runtime.h>

#define ALPHA_C   10.0f
#define INV_BETA  20.0f       // 1/0.05
#define EPS_C     1e-10f
#define FAR_DELTA 1e10f

// Quarter-wave per ray: 4 rays per wave, 16 lanes per ray, 8 samples per lane.
// Each lane issues 10 independent dwordx4 loads (160 B) up-front -> 2x the
// bytes in flight per wave vs the previous version; cross-lane chains shrink
// to width-16 (4-step scan, 4-step reduce).
__global__ __launch_bounds__(256) void volsdf_render_kernel(
    const float* __restrict__ sd,      // [N,128]
    const float* __restrict__ color,   // [N,128,3]
    const float* __restrict__ depth,   // [N,128]
    float* __restrict__ out,           // [N,3]
    int N)
{
    const int tid  = (int)(blockIdx.x * blockDim.x + threadIdx.x);
    const int wave = tid >> 6;
    const int lane = (int)(threadIdx.x & 63);
    const int g    = lane >> 4;        // ray slot within wave (0..3)
    const int gl   = lane & 15;        // lane within the 16-lane ray group
    const int ray  = wave * 4 + g;
    if (ray >= N) return;

    // ---- issue all loads up-front (10 independent dwordx4) ----
    const size_t rbase = (size_t)ray * 128 + (size_t)gl * 8;
    const float4 sdA = *reinterpret_cast<const float4*>(sd + rbase);
    const float4 sdB = *reinterpret_cast<const float4*>(sd + rbase + 4);
    const float4 dpA = *reinterpret_cast<const float4*>(depth + rbase);
    const float4 dpB = *reinterpret_cast<const float4*>(depth + rbase + 4);
    const float* cb  = color + (size_t)ray * 384 + (size_t)gl * 24;
    const float4 f0 = *reinterpret_cast<const float4*>(cb + 0);
    const float4 f1 = *reinterpret_cast<const float4*>(cb + 4);
    const float4 f2 = *reinterpret_cast<const float4*>(cb + 8);
    const float4 f3 = *reinterpret_cast<const float4*>(cb + 12);
    const float4 f4 = *reinterpret_cast<const float4*>(cb + 16);
    const float4 f5 = *reinterpret_cast<const float4*>(cb + 20);

    // ---- deltas (8 samples per lane) ----
    const float dnext = __shfl_down(dpA.x, 1, 16);  // depth[8gl+8]
    float dlt[8];
    dlt[0] = dpA.y - dpA.x;
    dlt[1] = dpA.z - dpA.y;
    dlt[2] = dpA.w - dpA.z;
    dlt[3] = dpB.x - dpA.w;
    dlt[4] = dpB.y - dpB.x;
    dlt[5] = dpB.z - dpB.y;
    dlt[6] = dpB.w - dpB.z;
    dlt[7] = (gl == 15) ? FAR_DELTA : (dnext - dpB.w);

    const float sdv[8] = {sdA.x, sdA.y, sdA.z, sdA.w, sdB.x, sdB.y, sdB.z, sdB.w};

    // ---- density -> per-step log transmittance t_i ----
    float t[8];
    #pragma unroll
    for (int i = 0; i < 8; ++i) {
        const float s = -sdv[i];
        const float e = __expf(-fabsf(s) * INV_BETA);
        const float den = ALPHA_C * ((s <= 0.0f) ? 0.5f * e : 1.0f - 0.5f * e);
        t[i] = -den * dlt[i] + EPS_C;
    }

    // in-lane cumulative sums c_i = sum_{j<i} t_j, lane total tl
    float c[8];
    c[0] = 0.0f;
    #pragma unroll
    for (int i = 1; i < 8; ++i) c[i] = c[i - 1] + t[i - 1];
    const float tl = c[7] + t[7];      // lane 15's tl ~ -1e11: never consumed

    // ---- width-16 inclusive scan; exclusive via shfl_up(incl,1) ----
    float incl = tl;
    #pragma unroll
    for (int off = 1; off < 16; off <<= 1) {
        const float up = __shfl_up(incl, off, 16);
        if (gl >= off) incl += up;
    }
    float excl = __shfl_up(incl, 1, 16);
    if (gl == 0) excl = 0.0f;
    // (never compute excl = incl - tl: catastrophic cancellation at gl==15)

    // ---- weights: T_i = exp(excl + c_i), w_i = T_i * (1 - exp(t_i)) ----
    float T = __expf(excl);
    float w[8];
    #pragma unroll
    for (int i = 0; i < 8; ++i) {
        const float et = __expf(t[i]);
        w[i] = T * (1.0f - et);
        T *= et;
    }

    // ---- weighted color accumulation ----
    float accr = w[0]*f0.x + w[1]*f0.w + w[2]*f1.z + w[3]*f2.y
               + w[4]*f3.x + w[5]*f3.w + w[6]*f4.z + w[7]*f5.y;
    float accg = w[0]*f0.y + w[1]*f1.x + w[2]*f1.w + w[3]*f2.z
               + w[4]*f3.y + w[5]*f4.x + w[6]*f4.w + w[7]*f5.z;
    float accb = w[0]*f0.z + w[1]*f1.y + w[2]*f2.x + w[3]*f2.w
               + w[4]*f3.z + w[5]*f4.y + w[6]*f5.x + w[7]*f5.w;

    // ---- width-16 reduction ----
    #pragma unroll
    for (int off = 8; off >= 1; off >>= 1) {
        accr += __shfl_xor(accr, off, 16);
        accg += __shfl_xor(accg, off, 16);
        accb += __shfl_xor(accb, off, 16);
    }

    if (gl == 0) {
        float* o = out + (size_t)ray * 3;
        o[0] = accr;
        o[1] = accg;
        o[2] = accb;
    }
}

extern "C" void kernel_launch(void* const* d_in, const int* in_sizes, int n_in,
                              void* d_out, int out_size, void* d_ws, size_t ws_size,
                              hipStream_t stream) {
    const float* sd    = (const float*)d_in[0];  // signed_distance [N,128]
    const float* color = (const float*)d_in[1];  // color [N,128,3]
    const float* depth = (const float*)d_in[2];  // depth_values [N,128]
    float* out = (float*)d_out;

    const int N = in_sizes[0] / 128;             // 65536
    const int nWaves = (N + 3) / 4;              // 4 rays per wave
    const int block = 256;
    const int grid = (nWaves * 64 + block - 1) / block;
    volsdf_render_kernel<<<grid, block, 0, stream>>>(sd, color, depth, out, N);
}